// Round 6
// baseline (2035.107 us; speedup 1.0000x reference)
//
#include <hip/hip_runtime.h>

// LowRankKVCache: out = X @ Vt^T @ Vt where Vt = top-64 eigenvectors of X^T X.
// 64 independent 2048x128 fp32 matrices (B*H = 4*16).
//
// Round 8: back to the PASSING odd-even register-resident Jacobi (round-1,
// jacobi 854us) -- the subspace-iteration branch is closed (gapless MP bulk
// spectrum => power filters can't resolve the 64/65 boundary; measured
// absmax 1.64). Round-1 was latency-chain bound (VALUBusy 19.7%, 4575
// cy/round vs ~900 cy issue). Fix: the exchange buffer only uses EVEN
// column slots => one matrix needs 32 KB, so TWO matrices fit per block.
// Each thread interleaves two independent Jacobi chains (2x ILP in the
// same latency shadow), same barrier structure as the verified kernel.
// Rotation made branchless (identity rotation == swap), removing octet
// divergence.
//
// ws layout (bytes):
//   [0, 4M)        G      (64 x 128x128 f32)   -- dead after jacobi
//   [4M, 8M)       Vfull  (64 x 128x128 f32)   -- dead after select_k
//   [8M, 8M+32K)   normg  (64 x 128 f32)       -- dead after select_k
//   [32M, 34M)     Vt     (64 x 64x128 f32)
//   [0, 32M)       W      (64 x 2048x64 f32)   -- overlays dead G/Vfull/normg
// total requirement: 34 MB of d_ws.

#define NM 64
#define SEQ 2048
#define DD 128
#define RR 64
#define NSWEEP 7
#define NROUND (NSWEEP * 64)  // one round = A-step + B-step; 64 rounds/sweep

#define OFF_VFULL (4194304ULL)
#define OFF_NORM  (8388608ULL)
#define OFF_VT    (33554432ULL)

__device__ __forceinline__ float dot4(float4 a, float4 b) {
  return a.x * b.x + a.y * b.y + a.z * b.z + a.w * b.w;
}

// DPP butterfly add over aligned 8-lane groups (VALU pipe).
template <int CTRL>
__device__ __forceinline__ float dpp_add(float x) {
  int y = __builtin_amdgcn_update_dpp(0, __float_as_int(x), CTRL, 0xf, 0xf, true);
  return x + __int_as_float(y);
}
__device__ __forceinline__ float red8(float x) {  // sum over aligned 8 lanes
  x = dpp_add<0xB1>(x);   // quad xor1
  x = dpp_add<0x4E>(x);   // quad xor2
  x = dpp_add<0x141>(x);  // row_half_mirror
  return x;
}

// Branchless Jacobi rotation from the pair's 2x2 Gram. Below-threshold
// (converged) pairs get exact identity (c=1, s=0); the caller always swaps,
// which matches the verified round-1 semantics (rotate-and-swap vs swap).
__device__ __forceinline__ void jrot(float app, float apq, float aqq,
                                     float& c, float& s) {
  bool ok = apq * apq > 1e-9f * app * aqq;
  float ap = ok ? apq : 1.f;            // NaN-safe denominator
  float tau = (aqq - app) / (2.f * ap);
  float tv = 1.f / (fabsf(tau) + sqrtf(1.f + tau * tau));
  tv = tau < 0.f ? -tv : tv;
  float cc = 1.f / sqrtf(1.f + tv * tv);
  float ss = tv * cc;
  c = ok ? cc : 1.f;
  s = ok ? ss : 0.f;
}

__device__ __forceinline__ void rot4(float c, float s, float4 p, float4 q,
                                     float4& np, float4& nq) {
  np.x = c * p.x - s * q.x;  nq.x = s * p.x + c * q.x;
  np.y = c * p.y - s * q.y;  nq.y = s * p.y + c * q.y;
  np.z = c * p.z - s * q.z;  nq.z = s * p.z + c * q.z;
  np.w = c * p.w - s * q.w;  nq.w = s * p.w + c * q.w;
}

// ---------------- K1: Gram G[m] = X[m]^T X[m] ----------------
__global__ __launch_bounds__(256) void gram_k(const float* __restrict__ X,
                                              float* __restrict__ G) {
  const int m = blockIdx.y;
  const int r0 = blockIdx.x * 32;  // G row tile (== X column tile)
  const int tid = threadIdx.x;
  __shared__ __align__(16) float Xs[64][128];  // 32 KB
  const float* Xm = X + (size_t)m * SEQ * DD;
  const int ti = tid >> 5;  // 0..7  -> G rows r0+4ti..+3
  const int tj = tid & 31;  // 0..31 -> G cols 4tj..+3
  float acc[4][4];
#pragma unroll
  for (int a = 0; a < 4; ++a)
#pragma unroll
    for (int b = 0; b < 4; ++b) acc[a][b] = 0.f;

  for (int s0 = 0; s0 < SEQ; s0 += 64) {
    __syncthreads();
    for (int t = tid; t < 2048; t += 256) {  // 64 rows x 32 float4
      int s = t >> 5, c4 = t & 31;
      *(float4*)&Xs[s][c4 * 4] =
          *(const float4*)&Xm[(size_t)(s0 + s) * DD + c4 * 4];
    }
    __syncthreads();
#pragma unroll 4
    for (int s = 0; s < 64; ++s) {
      float4 av = *(const float4*)&Xs[s][r0 + 4 * ti];
      float4 bv = *(const float4*)&Xs[s][4 * tj];
      acc[0][0] += av.x * bv.x; acc[0][1] += av.x * bv.y;
      acc[0][2] += av.x * bv.z; acc[0][3] += av.x * bv.w;
      acc[1][0] += av.y * bv.x; acc[1][1] += av.y * bv.y;
      acc[1][2] += av.y * bv.z; acc[1][3] += av.y * bv.w;
      acc[2][0] += av.z * bv.x; acc[2][1] += av.z * bv.y;
      acc[2][2] += av.z * bv.z; acc[2][3] += av.z * bv.w;
      acc[3][0] += av.w * bv.x; acc[3][1] += av.w * bv.y;
      acc[3][2] += av.w * bv.z; acc[3][3] += av.w * bv.w;
    }
  }
  float* Gm = G + (size_t)m * DD * DD;
#pragma unroll
  for (int a = 0; a < 4; ++a) {
    float4 v = make_float4(acc[a][0], acc[a][1], acc[a][2], acc[a][3]);
    *(float4*)&Gm[(size_t)(r0 + 4 * ti + a) * DD + 4 * tj] = v;
  }
}

// ---------------- K2: dual-matrix odd-even Jacobi, columns in registers ----
// 512 threads = 64 groups x 8 lanes; each group g owns slots (2g, 2g+1) of
// TWO matrices (ceA/coA, ceB/coB). Lane l holds float4s {l,l+8,l+16,l+24}
// of each 128-float column. Exchange buffers xA/xB hold only the EVEN
// column (slot g at x[g*32..g*32+31]) -> 32 KB each, 64 KB total.
__global__ __launch_bounds__(512) void jacobi2_k(const float* __restrict__ G,
                                                 float* __restrict__ Vfull,
                                                 float* __restrict__ normg) {
  const int m0 = 2 * blockIdx.x;       // first matrix
  const int m1 = 2 * blockIdx.x + 1;   // second matrix
  const int tid = threadIdx.x;
  const int g = tid >> 3;  // group 0..63
  const int l = tid & 7;   // lane in group
  __shared__ __align__(16) float4 xA[RR * 32];  // 32 KB
  __shared__ __align__(16) float4 xB[RR * 32];  // 32 KB

  // G is symmetric: column j of G == row j of G -> transpose-free load.
  const float4* GA = (const float4*)(G + (size_t)m0 * DD * DD);
  const float4* GB = (const float4*)(G + (size_t)m1 * DD * DD);
  float4 ceA[4], coA[4], ceB[4], coB[4];
#pragma unroll
  for (int j = 0; j < 4; ++j) {
    ceA[j] = GA[(size_t)(2 * g) * 32 + l + 8 * j];
    coA[j] = GA[(size_t)(2 * g + 1) * 32 + l + 8 * j];
    ceB[j] = GB[(size_t)(2 * g) * 32 + l + 8 * j];
    coB[j] = GB[(size_t)(2 * g + 1) * 32 + l + 8 * j];
  }
  const bool hasR = (g < 63);  // right B-pair (2g+1, 2g+2) exists
  const bool hasL = (g > 0);   // even col participates in left B-pair
  float4* hEA = &xA[g * 32];        // my even column's home (matrix A)
  float4* hRA = &xA[(g + 1) * 32];  // right neighbor's even home (A)
  float4* hEB = &xB[g * 32];
  float4* hRB = &xB[(g + 1) * 32];

  for (int round = 0; round < NROUND; ++round) {
    // ---- A-step: local pairs, register-only, both matrices (2x ILP) ----
    {
      float apA = 0.f, aqA = 0.f, axA = 0.f;
      float apB = 0.f, aqB = 0.f, axB = 0.f;
#pragma unroll
      for (int j = 0; j < 4; ++j) {
        apA += dot4(ceA[j], ceA[j]); axA += dot4(ceA[j], coA[j]);
        aqA += dot4(coA[j], coA[j]);
        apB += dot4(ceB[j], ceB[j]); axB += dot4(ceB[j], coB[j]);
        aqB += dot4(coB[j], coB[j]);
      }
      apA = red8(apA); axA = red8(axA); aqA = red8(aqA);
      apB = red8(apB); axB = red8(axB); aqB = red8(aqB);
      float cA, sA, cB, sB;
      jrot(apA, axA, aqA, cA, sA);
      jrot(apB, axB, aqB, cB, sB);
#pragma unroll
      for (int j = 0; j < 4; ++j) {
        float4 np, nq;
        rot4(cA, sA, ceA[j], coA[j], np, nq);
        ceA[j] = nq; coA[j] = np;  // always-swap
        rot4(cB, sB, ceB[j], coB[j], np, nq);
        ceB[j] = nq; coB[j] = np;
      }
    }
    // ---- B-step phase 1: publish my even columns (post-A values) ----
    if (hasL) {
#pragma unroll
      for (int j = 0; j < 4; ++j) {
        hEA[l + 8 * j] = ceA[j];
        hEB[l + 8 * j] = ceB[j];
      }
    }
    __syncthreads();
    // ---- B-step phase 2: rotate right pairs (odd local, neighbor-even
    //      from LDS), hand the updated neighbor columns back. ----
    if (hasR) {
      float4 rA[4], rB[4];
#pragma unroll
      for (int j = 0; j < 4; ++j) {
        rA[j] = hRA[l + 8 * j];
        rB[j] = hRB[l + 8 * j];
      }
      float apA = 0.f, aqA = 0.f, axA = 0.f;
      float apB = 0.f, aqB = 0.f, axB = 0.f;
#pragma unroll
      for (int j = 0; j < 4; ++j) {
        apA += dot4(coA[j], coA[j]); axA += dot4(coA[j], rA[j]);
        aqA += dot4(rA[j], rA[j]);
        apB += dot4(coB[j], coB[j]); axB += dot4(coB[j], rB[j]);
        aqB += dot4(rB[j], rB[j]);
      }
      apA = red8(apA); axA = red8(axA); aqA = red8(aqA);
      apB = red8(apB); axB = red8(axB); aqB = red8(aqB);
      float cA, sA, cB, sB;
      jrot(apA, axA, aqA, cA, sA);
      jrot(apB, axB, aqB, cB, sB);
#pragma unroll
      for (int j = 0; j < 4; ++j) {
        float4 np, nq;
        rot4(cA, sA, coA[j], rA[j], np, nq);
        hRA[l + 8 * j] = np;  // handoff (swap)
        coA[j] = nq;
        rot4(cB, sB, coB[j], rB[j], np, nq);
        hRB[l + 8 * j] = np;
        coB[j] = nq;
      }
    }
    __syncthreads();
    // ---- B-step phase 3: receive my updated even columns ----
    if (hasL) {
#pragma unroll
      for (int j = 0; j < 4; ++j) {
        ceA[j] = hEA[l + 8 * j];
        ceB[j] = hEB[l + 8 * j];
      }
    }
  }

  // Emit all 128 (unnormalized) eigenvector candidates + squared norms
  // for both matrices. Column order is arbitrary (select_k ranks by norm).
  float nA0 = 0.f, nA1 = 0.f, nB0 = 0.f, nB1 = 0.f;
#pragma unroll
  for (int j = 0; j < 4; ++j) {
    nA0 += dot4(ceA[j], ceA[j]); nA1 += dot4(coA[j], coA[j]);
    nB0 += dot4(ceB[j], ceB[j]); nB1 += dot4(coB[j], coB[j]);
  }
  nA0 = red8(nA0); nA1 = red8(nA1);
  nB0 = red8(nB0); nB1 = red8(nB1);
  float4* VeA = (float4*)(Vfull + ((size_t)m0 * DD + 2 * g) * DD);
  float4* VoA = (float4*)(Vfull + ((size_t)m0 * DD + 2 * g + 1) * DD);
  float4* VeB = (float4*)(Vfull + ((size_t)m1 * DD + 2 * g) * DD);
  float4* VoB = (float4*)(Vfull + ((size_t)m1 * DD + 2 * g + 1) * DD);
#pragma unroll
  for (int j = 0; j < 4; ++j) {
    VeA[l + 8 * j] = ceA[j];
    VoA[l + 8 * j] = coA[j];
    VeB[l + 8 * j] = ceB[j];
    VoB[l + 8 * j] = coB[j];
  }
  if (l == 0) {
    normg[m0 * DD + 2 * g] = nA0;      // |col|^2 = lambda^2
    normg[m0 * DD + 2 * g + 1] = nA1;
    normg[m1 * DD + 2 * g] = nB0;
    normg[m1 * DD + 2 * g + 1] = nB1;
  }
}

// ---------------- K2b: rank-select top-64 columns, normalize -> Vt ---------
__global__ __launch_bounds__(128) void select_k(const float* __restrict__ Vfull,
                                                const float* __restrict__ normg,
                                                float* __restrict__ Vt) {
  const int m = blockIdx.x;
  const int t = threadIdx.x;  // 0..127
  __shared__ float n[DD];
  __shared__ int inv[RR];
  __shared__ float scl[RR];
  n[t] = normg[m * DD + t];
  __syncthreads();
  float nt = n[t];
  int rk = 0;
  for (int k = 0; k < DD; ++k) {
    float nk = n[k];
    rk += ((nk > nt) || (nk == nt && k < t)) ? 1 : 0;
  }
  if (rk < RR) { inv[rk] = t; scl[rk] = 1.f / sqrtf(nt); }
  __syncthreads();
  for (int r = 0; r < RR; ++r) {
    Vt[((size_t)m * RR + r) * DD + t] =
        Vfull[((size_t)m * DD + inv[r]) * DD + t] * scl[r];
  }
}

// ---------------- K4: W = X @ Vt^T  (2048x64 per matrix) -------------------
__global__ __launch_bounds__(256) void gemm1_k(const float* __restrict__ X,
                                               const float* __restrict__ Vt,
                                               float* __restrict__ W) {
  const int m = blockIdx.y;
  const int s0 = blockIdx.x * 32;
  const int tid = threadIdx.x;
  __shared__ __align__(16) float VtT[128 * 68];  // [c][r], 34.8 KB
  __shared__ __align__(16) float Xs[32 * 132];   // padded, 16.9 KB
  const float* Vm = Vt + (size_t)m * RR * DD;
  for (int t = tid; t < RR * DD; t += 256) {
    int r = t >> 7, c = t & 127;
    VtT[c * 68 + r] = Vm[t];
  }
  const float* Xm = X + ((size_t)m * SEQ + s0) * DD;
  for (int t = tid; t < 1024; t += 256) {  // 32 rows x 32 float4
    int s = t >> 5, c4 = t & 31;
    *(float4*)&Xs[s * 132 + 4 * c4] = *(const float4*)&Xm[(size_t)s * DD + 4 * c4];
  }
  __syncthreads();
  const int ti = tid >> 4;  // 0..15 -> rows 2ti, 2ti+1
  const int tj = tid & 15;  // cols 4tj..+3
  float acc[2][4] = {{0.f, 0.f, 0.f, 0.f}, {0.f, 0.f, 0.f, 0.f}};
#pragma unroll 4
  for (int k = 0; k < DD; ++k) {
    float a0 = Xs[(2 * ti) * 132 + k];
    float a1 = Xs[(2 * ti + 1) * 132 + k];
    float4 bv = *(float4*)&VtT[k * 68 + 4 * tj];
    acc[0][0] += a0 * bv.x; acc[0][1] += a0 * bv.y;
    acc[0][2] += a0 * bv.z; acc[0][3] += a0 * bv.w;
    acc[1][0] += a1 * bv.x; acc[1][1] += a1 * bv.y;
    acc[1][2] += a1 * bv.z; acc[1][3] += a1 * bv.w;
  }
  float* Wm = W + ((size_t)m * SEQ + s0) * RR;
#pragma unroll
  for (int d = 0; d < 2; ++d) {
    float4 v = make_float4(acc[d][0], acc[d][1], acc[d][2], acc[d][3]);
    *(float4*)&Wm[(size_t)(2 * ti + d) * RR + 4 * tj] = v;
  }
}

// ---------------- K5: out = W @ Vt  (2048x128 per matrix) ------------------
__global__ __launch_bounds__(256) void gemm2_k(const float* __restrict__ W,
                                               const float* __restrict__ Vt,
                                               float* __restrict__ out) {
  const int m = blockIdx.y;
  const int s0 = blockIdx.x * 32;
  const int tid = threadIdx.x;
  __shared__ __align__(16) float Vts[64 * 132];  // 33.8 KB
  __shared__ __align__(16) float Ws[32 * 68];    // 8.7 KB
  const float* Vm = Vt + (size_t)m * RR * DD;
  for (int t = tid; t < 2048; t += 256) {  // 64 rows x 32 float4
    int r = t >> 5, c4 = t & 31;
    *(float4*)&Vts[r * 132 + 4 * c4] = *(const float4*)&Vm[(size_t)r * DD + 4 * c4];
  }
  const float* Wm = W + ((size_t)m * SEQ + s0) * RR;
  for (int t = tid; t < 512; t += 256) {  // 32 rows x 16 float4
    int s = t >> 4, c4 = t & 15;
    *(float4*)&Ws[s * 68 + 4 * c4] = *(const float4*)&Wm[(size_t)s * RR + 4 * c4];
  }
  __syncthreads();
  const int ti = tid >> 5;  // 0..7 -> rows 4ti..+3
  const int tj = tid & 31;  // cols 4tj..+3
  float acc[4][4] = {{0.f,0.f,0.f,0.f},{0.f,0.f,0.f,0.f},
                     {0.f,0.f,0.f,0.f},{0.f,0.f,0.f,0.f}};
#pragma unroll 4
  for (int k = 0; k < RR; ++k) {
    float4 bv = *(float4*)&Vts[k * 132 + 4 * tj];
    float a0 = Ws[(4 * ti + 0) * 68 + k];
    float a1 = Ws[(4 * ti + 1) * 68 + k];
    float a2 = Ws[(4 * ti + 2) * 68 + k];
    float a3 = Ws[(4 * ti + 3) * 68 + k];
    acc[0][0] += a0 * bv.x; acc[0][1] += a0 * bv.y;
    acc[0][2] += a0 * bv.z; acc[0][3] += a0 * bv.w;
    acc[1][0] += a1 * bv.x; acc[1][1] += a1 * bv.y;
    acc[1][2] += a1 * bv.z; acc[1][3] += a1 * bv.w;
    acc[2][0] += a2 * bv.x; acc[2][1] += a2 * bv.y;
    acc[2][2] += a2 * bv.z; acc[2][3] += a2 * bv.w;
    acc[3][0] += a3 * bv.x; acc[3][1] += a3 * bv.y;
    acc[3][2] += a3 * bv.z; acc[3][3] += a3 * bv.w;
  }
  float* Om = out + ((size_t)m * SEQ + s0) * DD;
#pragma unroll
  for (int d = 0; d < 4; ++d) {
    float4 v = make_float4(acc[d][0], acc[d][1], acc[d][2], acc[d][3]);
    *(float4*)&Om[(size_t)(4 * ti + d) * DD + 4 * tj] = v;
  }
}

extern "C" void kernel_launch(void* const* d_in, const int* in_sizes, int n_in,
                              void* d_out, int out_size, void* d_ws, size_t ws_size,
                              hipStream_t stream) {
  (void)in_sizes; (void)n_in; (void)out_size; (void)ws_size;
  const float* X = (const float*)d_in[0];  // rank (d_in[1]) is fixed at 64
  float* out = (float*)d_out;
  char* ws = (char*)d_ws;
  float* G = (float*)ws;
  float* Vfull = (float*)(ws + OFF_VFULL);
  float* normg = (float*)(ws + OFF_NORM);
  float* Vt = (float*)(ws + OFF_VT);
  float* W = (float*)ws;  // overlays dead G/Vfull/normg

  gram_k<<<dim3(4, NM), 256, 0, stream>>>(X, G);
  jacobi2_k<<<NM / 2, 512, 0, stream>>>(G, Vfull, normg);
  select_k<<<NM, 128, 0, stream>>>(Vfull, normg, Vt);
  gemm1_k<<<dim3(SEQ / 32, NM), 256, 0, stream>>>(X, Vt, W);
  gemm2_k<<<dim3(SEQ / 32, NM), 256, 0, stream>>>(W, Vt, out);
}

// Round 7
// 909.465 us; speedup vs baseline: 2.2377x; 2.2377x over previous
//
#include <hip/hip_runtime.h>

// LowRankKVCache: out = X @ Vt^T @ Vt where Vt = top-64 eigenvectors of X^T X.
// 64 independent 2048x128 fp32 matrices (B*H = 4*16).
//
// Round 9: verified round-1 odd-even register-resident Jacobi (854us) with
// two surgical cuts, per the R6 null-result (per-round cost = serialized
// DS+VALU issue; reduce work, not sync structure):
//  (1) norm-carrying: app/aqq update analytically (app'=app-tv*apq,
//      aqq'=aqq+tv*apq, trace-preserving); only the cross-dot apq is fresh.
//      Saves 2 dots + 2 red8 per rotation. Final norms recomputed exactly.
//  (2) NSWEEP 7->6 (R1@7 passed at 0.0195 vs threshold 0.09; sweep 7 is
//      quadratic-regime polish). 384 rounds instead of 448.
// Exchange buffer: only EVEN slots transit -> 32 KB (+256 B norm array).
//
// ws layout (bytes):
//   [0, 4M)        G      (64 x 128x128 f32)   -- dead after jacobi
//   [4M, 8M)       Vfull  (64 x 128x128 f32)   -- dead after select_k
//   [8M, 8M+32K)   normg  (64 x 128 f32)       -- dead after select_k
//   [32M, 34M)     Vt     (64 x 64x128 f32)
//   [0, 32M)       W      (64 x 2048x64 f32)   -- overlays dead G/Vfull/normg
// total requirement: 34 MB of d_ws.

#define NM 64
#define SEQ 2048
#define DD 128
#define RR 64
#define NSWEEP 6
#define NROUND (NSWEEP * 64)  // one round = A-step + B-step; 64 rounds/sweep

#define OFF_VFULL (4194304ULL)
#define OFF_NORM  (8388608ULL)
#define OFF_VT    (33554432ULL)

__device__ __forceinline__ float dot4(float4 a, float4 b) {
  return a.x * b.x + a.y * b.y + a.z * b.z + a.w * b.w;
}

// DPP butterfly add over aligned 8-lane groups (VALU pipe).
template <int CTRL>
__device__ __forceinline__ float dpp_add(float x) {
  int y = __builtin_amdgcn_update_dpp(0, __float_as_int(x), CTRL, 0xf, 0xf, true);
  return x + __int_as_float(y);
}
__device__ __forceinline__ float red8(float x) {  // sum over aligned 8 lanes
  x = dpp_add<0xB1>(x);   // quad xor1
  x = dpp_add<0x4E>(x);   // quad xor2
  x = dpp_add<0x141>(x);  // row_half_mirror
  return x;
}

// Branchless Jacobi rotation from (app, apq, aqq). Converged pairs get exact
// identity (c=1, s=0, tv=0); caller always swaps. tv also drives the
// analytic norm update: app' = app - tv*apq, aqq' = aqq + tv*apq.
__device__ __forceinline__ void jrot(float app, float apq, float aqq,
                                     float& c, float& s, float& tv) {
  bool ok = apq * apq > 1e-9f * app * aqq;
  float ap = ok ? apq : 1.f;            // NaN-safe denominator
  float tau = (aqq - app) / (2.f * ap);
  float t = 1.f / (fabsf(tau) + sqrtf(1.f + tau * tau));
  t = tau < 0.f ? -t : t;
  float cc = 1.f / sqrtf(1.f + t * t);
  float ss = t * cc;
  c = ok ? cc : 1.f;
  s = ok ? ss : 0.f;
  tv = ok ? t : 0.f;
}

__device__ __forceinline__ void rot4(float c, float s, float4 p, float4 q,
                                     float4& np, float4& nq) {
  np.x = c * p.x - s * q.x;  nq.x = s * p.x + c * q.x;
  np.y = c * p.y - s * q.y;  nq.y = s * p.y + c * q.y;
  np.z = c * p.z - s * q.z;  nq.z = s * p.z + c * q.z;
  np.w = c * p.w - s * q.w;  nq.w = s * p.w + c * q.w;
}

// ---------------- K1: Gram G[m] = X[m]^T X[m] ----------------
__global__ __launch_bounds__(256) void gram_k(const float* __restrict__ X,
                                              float* __restrict__ G) {
  const int m = blockIdx.y;
  const int r0 = blockIdx.x * 32;  // G row tile (== X column tile)
  const int tid = threadIdx.x;
  __shared__ __align__(16) float Xs[64][128];  // 32 KB
  const float* Xm = X + (size_t)m * SEQ * DD;
  const int ti = tid >> 5;  // 0..7  -> G rows r0+4ti..+3
  const int tj = tid & 31;  // 0..31 -> G cols 4tj..+3
  float acc[4][4];
#pragma unroll
  for (int a = 0; a < 4; ++a)
#pragma unroll
    for (int b = 0; b < 4; ++b) acc[a][b] = 0.f;

  for (int s0 = 0; s0 < SEQ; s0 += 64) {
    __syncthreads();
    for (int t = tid; t < 2048; t += 256) {  // 64 rows x 32 float4
      int s = t >> 5, c4 = t & 31;
      *(float4*)&Xs[s][c4 * 4] =
          *(const float4*)&Xm[(size_t)(s0 + s) * DD + c4 * 4];
    }
    __syncthreads();
#pragma unroll 4
    for (int s = 0; s < 64; ++s) {
      float4 av = *(const float4*)&Xs[s][r0 + 4 * ti];
      float4 bv = *(const float4*)&Xs[s][4 * tj];
      acc[0][0] += av.x * bv.x; acc[0][1] += av.x * bv.y;
      acc[0][2] += av.x * bv.z; acc[0][3] += av.x * bv.w;
      acc[1][0] += av.y * bv.x; acc[1][1] += av.y * bv.y;
      acc[1][2] += av.y * bv.z; acc[1][3] += av.y * bv.w;
      acc[2][0] += av.z * bv.x; acc[2][1] += av.z * bv.y;
      acc[2][2] += av.z * bv.z; acc[2][3] += av.z * bv.w;
      acc[3][0] += av.w * bv.x; acc[3][1] += av.w * bv.y;
      acc[3][2] += av.w * bv.z; acc[3][3] += av.w * bv.w;
    }
  }
  float* Gm = G + (size_t)m * DD * DD;
#pragma unroll
  for (int a = 0; a < 4; ++a) {
    float4 v = make_float4(acc[a][0], acc[a][1], acc[a][2], acc[a][3]);
    *(float4*)&Gm[(size_t)(r0 + 4 * ti + a) * DD + 4 * tj] = v;
  }
}

// ---------------- K2: odd-even Jacobi, register columns + carried norms ----
// 512 threads = 64 groups x 8 lanes. Group g owns slots (2g, 2g+1) in VGPRs
// plus their squared norms (nce, nco). Lane l holds float4s {l,l+8,l+16,l+24}
// of each column. Exchange buffer holds only EVEN columns (slot g at
// xch[g*32..g*32+31], 32 KB) + a 64-float norm array.
__global__ __launch_bounds__(512) void jacobi_nc_k(const float* __restrict__ G,
                                                   float* __restrict__ Vfull,
                                                   float* __restrict__ normg) {
  const int m = blockIdx.x;
  const int tid = threadIdx.x;
  const int g = tid >> 3;  // group 0..63
  const int l = tid & 7;   // lane in group
  __shared__ __align__(16) float4 xch[RR * 32];  // 32 KB (even slots only)
  __shared__ float nrm[RR];                      // norms of transiting evens

  // G is symmetric: column j of G == row j of G -> transpose-free load.
  const float4* Gm4 = (const float4*)(G + (size_t)m * DD * DD);
  float4 ce[4], co[4];
#pragma unroll
  for (int j = 0; j < 4; ++j) {
    ce[j] = Gm4[(size_t)(2 * g) * 32 + l + 8 * j];
    co[j] = Gm4[(size_t)(2 * g + 1) * 32 + l + 8 * j];
  }
  // Initial norms (exact, once).
  float nce = 0.f, nco = 0.f;
#pragma unroll
  for (int j = 0; j < 4; ++j) {
    nce += dot4(ce[j], ce[j]);
    nco += dot4(co[j], co[j]);
  }
  nce = red8(nce);
  nco = red8(nco);

  const bool hasR = (g < 63);  // right B-pair (2g+1, 2g+2) exists
  const bool hasL = (g > 0);   // even col participates in left B-pair
  float4* hE = &xch[g * 32];        // my even column's home
  float4* hR = &xch[(g + 1) * 32];  // right neighbor's even home

  for (int round = 0; round < NROUND; ++round) {
    // ---- A-step: local pair (2g, 2g+1), register-only, no barrier ----
    {
      float apq = 0.f;
#pragma unroll
      for (int j = 0; j < 4; ++j) apq += dot4(ce[j], co[j]);
      apq = red8(apq);
      float c, s, tv;
      jrot(nce, apq, nco, c, s, tv);  // app = nce, aqq = nco
#pragma unroll
      for (int j = 0; j < 4; ++j) {
        float4 np, nq;
        rot4(c, s, ce[j], co[j], np, nq);
        ce[j] = nq; co[j] = np;  // always-swap
      }
      float t = nce;
      nce = nco + tv * apq;  // norm(nq) = aqq + tv*apq
      nco = t - tv * apq;    // norm(np) = app - tv*apq
    }
    // ---- B-step phase 1: publish my even column + its norm ----
    if (hasL) {
#pragma unroll
      for (int j = 0; j < 4; ++j) hE[l + 8 * j] = ce[j];
      if (l == 0) nrm[g] = nce;
    }
    __syncthreads();
    // ---- B-step phase 2: rotate right pair (co local, neighbor-even from
    //      LDS), hand back the updated column and norm. ----
    if (hasR) {
      float4 r4[4];
#pragma unroll
      for (int j = 0; j < 4; ++j) r4[j] = hR[l + 8 * j];
      float nr = nrm[g + 1];
      float apq = 0.f;
#pragma unroll
      for (int j = 0; j < 4; ++j) apq += dot4(co[j], r4[j]);
      apq = red8(apq);
      float c, s, tv;
      jrot(nco, apq, nr, c, s, tv);  // app = nco (p=co), aqq = nr (q=r)
#pragma unroll
      for (int j = 0; j < 4; ++j) {
        float4 np, nq;
        rot4(c, s, co[j], r4[j], np, nq);
        hR[l + 8 * j] = np;  // handoff (swap): neighbor even <- np
        co[j] = nq;          // my odd <- nq
      }
      if (l == 0) nrm[g + 1] = nco - tv * apq;  // norm(np) = app - tv*apq
      nco = nr + tv * apq;                       // norm(nq) = aqq + tv*apq
    }
    __syncthreads();
    // ---- B-step phase 3: receive my updated even column + norm ----
    if (hasL) {
#pragma unroll
      for (int j = 0; j < 4; ++j) ce[j] = hE[l + 8 * j];
      nce = nrm[g];
    }
  }

  // Emit all 128 (unnormalized) eigenvector candidates + EXACT squared
  // norms (drift-free). Column order is arbitrary -- select_k ranks by norm.
  float ne = 0.f, no_ = 0.f;
#pragma unroll
  for (int j = 0; j < 4; ++j) {
    ne += dot4(ce[j], ce[j]);
    no_ += dot4(co[j], co[j]);
  }
  ne = red8(ne);
  no_ = red8(no_);
  float4* Ve = (float4*)(Vfull + ((size_t)m * DD + 2 * g) * DD);
  float4* Vo = (float4*)(Vfull + ((size_t)m * DD + 2 * g + 1) * DD);
#pragma unroll
  for (int j = 0; j < 4; ++j) {
    Ve[l + 8 * j] = ce[j];
    Vo[l + 8 * j] = co[j];
  }
  if (l == 0) {
    normg[m * DD + 2 * g] = ne;      // |col|^2 = lambda^2
    normg[m * DD + 2 * g + 1] = no_;
  }
}

// ---------------- K2b: rank-select top-64 columns, normalize -> Vt ---------
__global__ __launch_bounds__(128) void select_k(const float* __restrict__ Vfull,
                                                const float* __restrict__ normg,
                                                float* __restrict__ Vt) {
  const int m = blockIdx.x;
  const int t = threadIdx.x;  // 0..127
  __shared__ float n[DD];
  __shared__ int inv[RR];
  __shared__ float scl[RR];
  n[t] = normg[m * DD + t];
  __syncthreads();
  float nt = n[t];
  int rk = 0;
  for (int k = 0; k < DD; ++k) {
    float nk = n[k];
    rk += ((nk > nt) || (nk == nt && k < t)) ? 1 : 0;
  }
  if (rk < RR) { inv[rk] = t; scl[rk] = 1.f / sqrtf(nt); }
  __syncthreads();
  for (int r = 0; r < RR; ++r) {
    Vt[((size_t)m * RR + r) * DD + t] =
        Vfull[((size_t)m * DD + inv[r]) * DD + t] * scl[r];
  }
}

// ---------------- K4: W = X @ Vt^T  (2048x64 per matrix) -------------------
__global__ __launch_bounds__(256) void gemm1_k(const float* __restrict__ X,
                                               const float* __restrict__ Vt,
                                               float* __restrict__ W) {
  const int m = blockIdx.y;
  const int s0 = blockIdx.x * 32;
  const int tid = threadIdx.x;
  __shared__ __align__(16) float VtT[128 * 68];  // [c][r], 34.8 KB
  __shared__ __align__(16) float Xs[32 * 132];   // padded, 16.9 KB
  const float* Vm = Vt + (size_t)m * RR * DD;
  for (int t = tid; t < RR * DD; t += 256) {
    int r = t >> 7, c = t & 127;
    VtT[c * 68 + r] = Vm[t];
  }
  const float* Xm = X + ((size_t)m * SEQ + s0) * DD;
  for (int t = tid; t < 1024; t += 256) {  // 32 rows x 32 float4
    int s = t >> 5, c4 = t & 31;
    *(float4*)&Xs[s * 132 + 4 * c4] = *(const float4*)&Xm[(size_t)s * DD + 4 * c4];
  }
  __syncthreads();
  const int ti = tid >> 4;  // 0..15 -> rows 2ti, 2ti+1
  const int tj = tid & 15;  // cols 4tj..+3
  float acc[2][4] = {{0.f, 0.f, 0.f, 0.f}, {0.f, 0.f, 0.f, 0.f}};
#pragma unroll 4
  for (int k = 0; k < DD; ++k) {
    float a0 = Xs[(2 * ti) * 132 + k];
    float a1 = Xs[(2 * ti + 1) * 132 + k];
    float4 bv = *(float4*)&VtT[k * 68 + 4 * tj];
    acc[0][0] += a0 * bv.x; acc[0][1] += a0 * bv.y;
    acc[0][2] += a0 * bv.z; acc[0][3] += a0 * bv.w;
    acc[1][0] += a1 * bv.x; acc[1][1] += a1 * bv.y;
    acc[1][2] += a1 * bv.z; acc[1][3] += a1 * bv.w;
  }
  float* Wm = W + ((size_t)m * SEQ + s0) * RR;
#pragma unroll
  for (int d = 0; d < 2; ++d) {
    float4 v = make_float4(acc[d][0], acc[d][1], acc[d][2], acc[d][3]);
    *(float4*)&Wm[(size_t)(2 * ti + d) * RR + 4 * tj] = v;
  }
}

// ---------------- K5: out = W @ Vt  (2048x128 per matrix) ------------------
__global__ __launch_bounds__(256) void gemm2_k(const float* __restrict__ W,
                                               const float* __restrict__ Vt,
                                               float* __restrict__ out) {
  const int m = blockIdx.y;
  const int s0 = blockIdx.x * 32;
  const int tid = threadIdx.x;
  __shared__ __align__(16) float Vts[64 * 132];  // 33.8 KB
  __shared__ __align__(16) float Ws[32 * 68];    // 8.7 KB
  const float* Vm = Vt + (size_t)m * RR * DD;
  for (int t = tid; t < 2048; t += 256) {  // 64 rows x 32 float4
    int r = t >> 5, c4 = t & 31;
    *(float4*)&Vts[r * 132 + 4 * c4] = *(const float4*)&Vm[(size_t)r * DD + 4 * c4];
  }
  const float* Wm = W + ((size_t)m * SEQ + s0) * RR;
  for (int t = tid; t < 512; t += 256) {  // 32 rows x 16 float4
    int s = t >> 4, c4 = t & 15;
    *(float4*)&Ws[s * 68 + 4 * c4] = *(const float4*)&Wm[(size_t)s * RR + 4 * c4];
  }
  __syncthreads();
  const int ti = tid >> 5;  // 0..7 -> rows 4ti..+3
  const int tj = tid & 31;  // cols 4tj..+3
  float acc[4][4] = {{0.f,0.f,0.f,0.f},{0.f,0.f,0.f,0.f},
                     {0.f,0.f,0.f,0.f},{0.f,0.f,0.f,0.f}};
#pragma unroll 4
  for (int k = 0; k < RR; ++k) {
    float4 bv = *(float4*)&Vts[k * 132 + 4 * tj];
    float a0 = Ws[(4 * ti + 0) * 68 + k];
    float a1 = Ws[(4 * ti + 1) * 68 + k];
    float a2 = Ws[(4 * ti + 2) * 68 + k];
    float a3 = Ws[(4 * ti + 3) * 68 + k];
    acc[0][0] += a0 * bv.x; acc[0][1] += a0 * bv.y;
    acc[0][2] += a0 * bv.z; acc[0][3] += a0 * bv.w;
    acc[1][0] += a1 * bv.x; acc[1][1] += a1 * bv.y;
    acc[1][2] += a1 * bv.z; acc[1][3] += a1 * bv.w;
    acc[2][0] += a2 * bv.x; acc[2][1] += a2 * bv.y;
    acc[2][2] += a2 * bv.z; acc[2][3] += a2 * bv.w;
    acc[3][0] += a3 * bv.x; acc[3][1] += a3 * bv.y;
    acc[3][2] += a3 * bv.z; acc[3][3] += a3 * bv.w;
  }
  float* Om = out + ((size_t)m * SEQ + s0) * DD;
#pragma unroll
  for (int d = 0; d < 4; ++d) {
    float4 v = make_float4(acc[d][0], acc[d][1], acc[d][2], acc[d][3]);
    *(float4*)&Om[(size_t)(4 * ti + d) * DD + 4 * tj] = v;
  }
}

extern "C" void kernel_launch(void* const* d_in, const int* in_sizes, int n_in,
                              void* d_out, int out_size, void* d_ws, size_t ws_size,
                              hipStream_t stream) {
  (void)in_sizes; (void)n_in; (void)out_size; (void)ws_size;
  const float* X = (const float*)d_in[0];  // rank (d_in[1]) is fixed at 64
  float* out = (float*)d_out;
  char* ws = (char*)d_ws;
  float* G = (float*)ws;
  float* Vfull = (float*)(ws + OFF_VFULL);
  float* normg = (float*)(ws + OFF_NORM);
  float* Vt = (float*)(ws + OFF_VT);
  float* W = (float*)ws;  // overlays dead G/Vfull/normg

  gram_k<<<dim3(4, NM), 256, 0, stream>>>(X, G);
  jacobi_nc_k<<<NM, 512, 0, stream>>>(G, Vfull, normg);
  select_k<<<NM, 128, 0, stream>>>(Vfull, normg, Vt);
  gemm1_k<<<dim3(SEQ / 32, NM), 256, 0, stream>>>(X, Vt, W);
  gemm2_k<<<dim3(SEQ / 32, NM), 256, 0, stream>>>(W, Vt, out);
}